// Round 5
// baseline (214.137 us; speedup 1.0000x reference)
//
#include <hip/hip_runtime.h>

#define IN_DIM    1024
#define CTX_DIM   768
#define NUM_HEADS 16
#define HEAD_DIM  64
#define BATCH     8
#define NQ        1024
#define NKV       512
#define C2LOG     0.18033688f   // (1/sqrt(64)) * log2(e)

typedef __attribute__((ext_vector_type(8)))  _Float16 f16x8;
typedef __attribute__((ext_vector_type(4)))  _Float16 f16x4;
typedef __attribute__((ext_vector_type(2)))  _Float16 f16x2;
typedef __attribute__((ext_vector_type(4)))  float    f32x4;
typedef __attribute__((ext_vector_type(16))) float    f32x16;

// async global->LDS, 16B per lane. lds dest is wave-uniform base (+lane*16).
__device__ __forceinline__ void async16(const void* g, void* l) {
    __builtin_amdgcn_global_load_lds(
        (const __attribute__((address_space(1))) void*)g,
        (__attribute__((address_space(3))) void*)l, 16, 0, 0);
}

__device__ __forceinline__ float fexp2(float x) {
    float r; asm("v_exp_f32 %0, %1" : "=v"(r) : "v"(x)); return r;
}

// v_permlane32_swap_b32: a[32:63] <-> b[0:31]
__device__ __forceinline__ void plswap(int& a, int& b) {
    asm volatile("v_permlane32_swap_b32 %0, %1" : "+v"(a), "+v"(b));
}

// ---------------------------------------------------------------------------
// fp32 -> fp16 conversion of x, context, Wq, Wk, Wv, Wo (one contiguous dst).
// Wq segment is pre-scaled by C2LOG (folds attention scale into Q-proj).
// ---------------------------------------------------------------------------
__global__ __launch_bounds__(256)
void cvt6(const float* __restrict__ s0, const float* __restrict__ s1,
          const float* __restrict__ s2, const float* __restrict__ s3,
          const float* __restrict__ s4, const float* __restrict__ s5,
          _Float16* __restrict__ dst)
{
    const int stride = gridDim.x * blockDim.x;
    for (int i = blockIdx.x * blockDim.x + threadIdx.x; i < 3801088; i += stride) {
        const float* s; int loc;
        if      (i < 2097152) { s = s0; loc = i; }
        else if (i < 2883584) { s = s1; loc = i - 2097152; }
        else if (i < 3145728) { s = s2; loc = i - 2883584; }
        else if (i < 3342336) { s = s3; loc = i - 3145728; }
        else if (i < 3538944) { s = s4; loc = i - 3342336; }
        else                  { s = s5; loc = i - 3538944; }
        float sc = (i >= 2883584 && i < 3145728) ? C2LOG : 1.0f;  // Wq scaled
        float4 v = *(const float4*)(s + (size_t)loc * 4);
        f16x4 o;
        o.x = (_Float16)(v.x * sc); o.y = (_Float16)(v.y * sc);
        o.z = (_Float16)(v.z * sc); o.w = (_Float16)(v.w * sc);
        *(f16x4*)(dst + (size_t)i * 4) = o;
    }
}

// ---------------------------------------------------------------------------
// Merged Q/K/V projection. 1024 blocks, uniform BM=BN=128, BK=64, 4 waves.
// tile<512: Q = xh@WqT*C2LOG (+bq*C2LOG), K=1024.
// tile<768: K = ctx@WkT + bk, K=768.
// else    : V = ctx@WvT + bv, K=768, epilogue writes V^T [b,h,d,kv].
// Double-buffered LDS staging via global_load_lds (swizzled source).
// ---------------------------------------------------------------------------
__global__ __launch_bounds__(256)
void proj_qkv(const _Float16* __restrict__ xh, const _Float16* __restrict__ ctxh,
              const _Float16* __restrict__ wqh, const float* __restrict__ bq,
              const _Float16* __restrict__ wkh, const float* __restrict__ bk,
              const _Float16* __restrict__ wvh, const float* __restrict__ bv,
              _Float16* __restrict__ Qh, _Float16* __restrict__ Kh,
              _Float16* __restrict__ Vth)
{
    constexpr int BK = 64, CL = 136;
    __shared__ alignas(16) union {
        struct { _Float16 A[2][128 * BK]; _Float16 W[2][128 * BK]; } st;  // 64 KB
        _Float16 ce[128 * CL];
    } lds;

    const int tid = threadIdx.x;
    const int l   = tid & 63;
    const int w   = tid >> 6;
    const int wr  = w >> 1, wc = w & 1;

    // XCD-chunked decode over 1024 tiles
    const int tile = ((int)blockIdx.x & 7) * 128 + ((int)blockIdx.x >> 3);
    const _Float16* A; const _Float16* W; const float* bias; _Float16* C;
    int K, m0, n0, mode;
    if (tile < 512)      { mode = 0; A = xh;   W = wqh; bias = bq; C = Qh; K = 1024;
                           m0 = (tile >> 3) * 128;        n0 = (tile & 7) * 128; }
    else if (tile < 768) { int s = tile - 512; mode = 1; A = ctxh; W = wkh; bias = bk;
                           C = Kh; K = 768;
                           m0 = (s >> 3) * 128;           n0 = (s & 7) * 128; }
    else                 { int s = tile - 768; mode = 2; A = ctxh; W = wvh; bias = bv;
                           C = Vth; K = 768;
                           m0 = (s >> 3) * 128;           n0 = (s & 7) * 128; }

    int aOff[2][4], bOff[2][4];
    #pragma unroll
    for (int kk = 0; kk < 2; ++kk) {
        #pragma unroll
        for (int m = 0; m < 4; ++m) {
            int rr = wr * 64 + m * 16 + (l & 15);
            aOff[kk][m] = rr * 64 + (((kk * 4 + (l >> 4)) ^ (rr & 7)) * 8);
        }
        #pragma unroll
        for (int n = 0; n < 4; ++n) {
            int rr = wc * 64 + n * 16 + (l & 15);
            bOff[kk][n] = rr * 64 + (((kk * 4 + (l >> 4)) ^ (rr & 7)) * 8);
        }
    }

    f32x4 acc[4][4];
    #pragma unroll
    for (int m = 0; m < 4; ++m)
        #pragma unroll
        for (int n = 0; n < 4; ++n)
            acc[m][n] = (f32x4){0.f, 0.f, 0.f, 0.f};

#define GSTAGE(buf, k0) do {                                                    \
        _Pragma("unroll")                                                       \
        for (int it_ = 0; it_ < 4; ++it_) {                                     \
            int e = it_ * 256 + tid, r = e >> 3, p = e & 7;                     \
            async16(A + (size_t)(m0 + r) * K + (k0) + ((p ^ (r & 7)) * 8),      \
                    &lds.st.A[buf][(it_ * 256 + (tid & ~63)) * 8]);             \
        }                                                                       \
        _Pragma("unroll")                                                       \
        for (int it_ = 0; it_ < 4; ++it_) {                                     \
            int e = it_ * 256 + tid, r = e >> 3, p = e & 7;                     \
            async16(W + (size_t)(n0 + r) * K + (k0) + ((p ^ (r & 7)) * 8),      \
                    &lds.st.W[buf][(it_ * 256 + (tid & ~63)) * 8]);             \
        }                                                                       \
    } while (0)

    const int nk = K / BK;
    GSTAGE(0, 0);
    __syncthreads();

    for (int kt = 0; kt < nk; ++kt) {
        const int cur = kt & 1;
        if (kt + 1 < nk) GSTAGE(cur ^ 1, (kt + 1) * BK);

        const _Float16* As = lds.st.A[cur];
        const _Float16* Ws = lds.st.W[cur];
        #pragma unroll
        for (int kk = 0; kk < 2; ++kk) {
            f16x8 af[4], bf[4];
            #pragma unroll
            for (int m = 0; m < 4; ++m) af[m] = *(const f16x8*)&As[aOff[kk][m]];
            #pragma unroll
            for (int n = 0; n < 4; ++n) bf[n] = *(const f16x8*)&Ws[bOff[kk][n]];
            #pragma unroll
            for (int m = 0; m < 4; ++m)
                #pragma unroll
                for (int n = 0; n < 4; ++n)
                    acc[m][n] = __builtin_amdgcn_mfma_f32_16x16x32_f16(
                        af[m], bf[n], acc[m][n], 0, 0, 0);
        }
        __syncthreads();
    }
#undef GSTAGE

    const float bsc = (mode == 0) ? C2LOG : 1.0f;
    float bv_[4];
    #pragma unroll
    for (int n = 0; n < 4; ++n)
        bv_[n] = bias[n0 + wc * 64 + n * 16 + (l & 15)] * bsc;

    #pragma unroll
    for (int m = 0; m < 4; ++m)
        #pragma unroll
        for (int n = 0; n < 4; ++n)
            #pragma unroll
            for (int r = 0; r < 4; ++r) {
                int row = wr * 64 + m * 16 + (l >> 4) * 4 + r;
                int col = wc * 64 + n * 16 + (l & 15);
                lds.ce[row * CL + col] = (_Float16)(acc[m][n][r] + bv_[n]);
            }
    __syncthreads();

    if (mode == 2) {
        // V^T epilogue: Vth[((b*16+h)*64 + d)*NKV + kv], tile spans 2 heads
        const int bb = m0 >> 9, kv0 = m0 & 511, hh0 = n0 >> 6;
        #pragma unroll
        for (int it = 0; it < 8; ++it) {
            int i = it * 256 + tid;
            int d = i & 127, c = i >> 7;     // d-col, kv-chunk (8 kv each)
            f16x8 v;
            #pragma unroll
            for (int j = 0; j < 8; ++j) v[j] = lds.ce[(c * 8 + j) * CL + d];
            *(f16x8*)(Vth + ((size_t)(bb * 16 + hh0 + (d >> 6)) * 64 + (d & 63)) * NKV
                          + kv0 + c * 8) = v;
        }
    } else {
        #pragma unroll
        for (int it = 0; it < 8; ++it) {
            int i = it * 256 + tid;
            int r = i >> 4, s = i & 15;
            *(f16x8*)(C + (size_t)(m0 + r) * IN_DIM + n0 + s * 8) =
                *(const f16x8*)&lds.ce[r * CL + s * 8];
        }
    }
}

// ---------------------------------------------------------------------------
// Output GEMM: out[M,1024](f32) = Ah[M,1024](f16) @ Wo[1024,1024](f16)^T + bo
// Same 128x128x64 double-buffered structure.
// ---------------------------------------------------------------------------
__global__ __launch_bounds__(256)
void gemm_out(const _Float16* __restrict__ A, const _Float16* __restrict__ W,
              const float* __restrict__ bias, float* __restrict__ C)
{
    constexpr int BK = 64, K = 1024;
    __shared__ alignas(16) struct { _Float16 A[2][128 * BK]; _Float16 W[2][128 * BK]; } lds;

    const int tid = threadIdx.x;
    const int l   = tid & 63;
    const int w   = tid >> 6;
    const int wr  = w >> 1, wc = w & 1;

    const int per  = gridDim.x >> 3;
    const int tile = ((int)blockIdx.x & 7) * per + ((int)blockIdx.x >> 3);
    const int m0   = (tile >> 3) * 128;
    const int n0   = (tile & 7) * 128;

    int aOff[2][4], bOff[2][4];
    #pragma unroll
    for (int kk = 0; kk < 2; ++kk) {
        #pragma unroll
        for (int m = 0; m < 4; ++m) {
            int rr = wr * 64 + m * 16 + (l & 15);
            aOff[kk][m] = rr * 64 + (((kk * 4 + (l >> 4)) ^ (rr & 7)) * 8);
        }
        #pragma unroll
        for (int n = 0; n < 4; ++n) {
            int rr = wc * 64 + n * 16 + (l & 15);
            bOff[kk][n] = rr * 64 + (((kk * 4 + (l >> 4)) ^ (rr & 7)) * 8);
        }
    }

    f32x4 acc[4][4];
    #pragma unroll
    for (int m = 0; m < 4; ++m)
        #pragma unroll
        for (int n = 0; n < 4; ++n)
            acc[m][n] = (f32x4){0.f, 0.f, 0.f, 0.f};

#define GSTAGE(buf, k0) do {                                                    \
        _Pragma("unroll")                                                       \
        for (int it_ = 0; it_ < 4; ++it_) {                                     \
            int e = it_ * 256 + tid, r = e >> 3, p = e & 7;                     \
            async16(A + (size_t)(m0 + r) * K + (k0) + ((p ^ (r & 7)) * 8),      \
                    &lds.A[buf][(it_ * 256 + (tid & ~63)) * 8]);                \
        }                                                                       \
        _Pragma("unroll")                                                       \
        for (int it_ = 0; it_ < 4; ++it_) {                                     \
            int e = it_ * 256 + tid, r = e >> 3, p = e & 7;                     \
            async16(W + (size_t)(n0 + r) * K + (k0) + ((p ^ (r & 7)) * 8),      \
                    &lds.W[buf][(it_ * 256 + (tid & ~63)) * 8]);                \
        }                                                                       \
    } while (0)

    GSTAGE(0, 0);
    __syncthreads();

    for (int kt = 0; kt < 16; ++kt) {
        const int cur = kt & 1;
        if (kt + 1 < 16) GSTAGE(cur ^ 1, (kt + 1) * BK);

        const _Float16* As = lds.A[cur];
        const _Float16* Ws = lds.W[cur];
        #pragma unroll
        for (int kk = 0; kk < 2; ++kk) {
            f16x8 af[4], bf[4];
            #pragma unroll
            for (int m = 0; m < 4; ++m) af[m] = *(const f16x8*)&As[aOff[kk][m]];
            #pragma unroll
            for (int n = 0; n < 4; ++n) bf[n] = *(const f16x8*)&Ws[bOff[kk][n]];
            #pragma unroll
            for (int m = 0; m < 4; ++m)
                #pragma unroll
                for (int n = 0; n < 4; ++n)
                    acc[m][n] = __builtin_amdgcn_mfma_f32_16x16x32_f16(
                        af[m], bf[n], acc[m][n], 0, 0, 0);
        }
        __syncthreads();
    }
#undef GSTAGE

    float bv_[4];
    #pragma unroll
    for (int n = 0; n < 4; ++n)
        bv_[n] = bias[n0 + wc * 64 + n * 16 + (l & 15)];
    #pragma unroll
    for (int m = 0; m < 4; ++m)
        #pragma unroll
        for (int n = 0; n < 4; ++n)
            #pragma unroll
            for (int r = 0; r < 4; ++r) {
                int row = m0 + wr * 64 + m * 16 + (l >> 4) * 4 + r;
                int col = n0 + wc * 64 + n * 16 + (l & 15);
                C[(size_t)row * IN_DIM + col] = acc[m][n][r] + bv_[n];
            }
}

// ---------------------------------------------------------------------------
// MFMA flash attention — swapped-QK 32x32 structure (T12).
// Block = 128 q-rows of one (b,h); 4 waves x 32 q. KVBLK=64 double-buffered.
// Q arrives pre-scaled by SCALE*log2e (folded into Wq/bq).
// ---------------------------------------------------------------------------
__global__ __launch_bounds__(256)
void attn_mfma(const _Float16* __restrict__ Qh, const _Float16* __restrict__ Kh,
               const _Float16* __restrict__ Vt, _Float16* __restrict__ Ah)
{
    __shared__ alignas(16) union {
        struct { _Float16 K[2][64 * 64]; _Float16 V[2][64 * 64]; } st;   // 32 KB
        _Float16 ot[4][32 * 72];                                         // 18 KB
    } lds;

    const int tid = threadIdx.x;
    const int l = tid & 63, w = tid >> 6;
    const int hi = l >> 5, ln = l & 31;
    const int t  = ((int)blockIdx.x & 7) * 128 + ((int)blockIdx.x >> 3);
    const int qt = t & 7, h = (t >> 3) & 15, b = t >> 7;
    const int q0 = qt * 128;

    // Q as B-operand frags (already in exp2 domain via scaled Wq/bq)
    f16x8 qa[4];
    {
        const _Float16* qp = Qh + ((size_t)(b * NQ) + q0 + w * 32 + ln) * IN_DIM
                                + h * 64 + hi * 8;
        #pragma unroll
        for (int ks = 0; ks < 4; ++ks) qa[ks] = *(const f16x8*)(qp + ks * 16);
    }

    const _Float16* Kbase = Kh + (size_t)(b * NKV) * IN_DIM + h * 64;
    const _Float16* Vbase = Vt + ((size_t)(b * 16 + h) * 64) * NKV;

#define STAGE(buf, kv0) do {                                                     \
        _Pragma("unroll")                                                        \
        for (int it_ = 0; it_ < 2; ++it_) {                                      \
            int e = it_ * 256 + tid, r = e >> 3, p = e & 7;                      \
            async16(Kbase + (size_t)((kv0) + r) * IN_DIM + ((p ^ (r & 7)) * 8),  \
                    &lds.st.K[buf][(it_ * 256 + (tid & ~63)) * 8]);              \
        }                                                                        \
        _Pragma("unroll")                                                        \
        for (int it_ = 0; it_ < 2; ++it_) {                                      \
            int e = it_ * 256 + tid, r = e >> 3, p = e & 7;                      \
            async16(Vbase + (size_t)r * NKV + (kv0) + ((p ^ (r & 7)) * 8),       \
                    &lds.st.V[buf][(it_ * 256 + (tid & ~63)) * 8]);              \
        }                                                                        \
    } while (0)

    f32x16 oacc[2];
    #pragma unroll
    for (int dt = 0; dt < 2; ++dt)
        #pragma unroll
        for (int i = 0; i < 16; ++i) oacc[dt][i] = 0.f;
    float m2 = -1e30f, lr = 0.f;

    STAGE(0, 0);
    __syncthreads();

    for (int kt = 0; kt < NKV / 64; ++kt) {
        const int cur = kt & 1;
        if (kt < NKV / 64 - 1) STAGE(cur ^ 1, (kt + 1) * 64);

        // ---- S^T = K·Q^T ----
        f32x16 sf[2];
        #pragma unroll
        for (int st = 0; st < 2; ++st)
            #pragma unroll
            for (int i = 0; i < 16; ++i) sf[st][i] = 0.f;

        __builtin_amdgcn_s_setprio(1);
        #pragma unroll
        for (int st = 0; st < 2; ++st) {
            int kvr = st * 32 + ln;
            #pragma unroll
            for (int ks = 0; ks < 4; ++ks) {
                f16x8 kf = *(const f16x8*)
                    &lds.st.K[cur][kvr * 64 + (((ks * 2 + hi) ^ (kvr & 7)) * 8)];
                sf[st] = __builtin_amdgcn_mfma_f32_32x32x16_f16(kf, qa[ks], sf[st], 0, 0, 0);
            }
        }
        __builtin_amdgcn_s_setprio(0);

        // ---- softmax over 64 kv: register tree + one cross-half swap ----
        float t0[16];
        #pragma unroll
        for (int i = 0; i < 16; ++i) t0[i] = fmaxf(sf[0][i], sf[1][i]);
        #pragma unroll
        for (int s = 8; s; s >>= 1)
            #pragma unroll
            for (int i = 0; i < s; ++i) t0[i] = fmaxf(t0[i], t0[i + s]);
        float pmax = fmaxf(t0[0], __shfl_xor(t0[0], 32));

        if (__any((int)(pmax > m2 + 8.f))) {   // defer-rescale (T13)
            float mn = fmaxf(m2, pmax);
            float corr = fexp2(m2 - mn);
            lr *= corr; m2 = mn;
            #pragma unroll
            for (int dt = 0; dt < 2; ++dt)
                #pragma unroll
                for (int i = 0; i < 16; ++i) oacc[dt][i] *= corr;
        }

        #pragma unroll
        for (int st = 0; st < 2; ++st)
            #pragma unroll
            for (int i = 0; i < 16; ++i) sf[st][i] = fexp2(sf[st][i] - m2);

        #pragma unroll
        for (int i = 0; i < 16; ++i) t0[i] = sf[0][i] + sf[1][i];
        #pragma unroll
        for (int s = 8; s; s >>= 1)
            #pragma unroll
            for (int i = 0; i < s; ++i) t0[i] += t0[i + s];
        lr += t0[0] + __shfl_xor(t0[0], 32);

        // ---- pack P to f16 pairs, permlane-swap into B-frag order ----
        int wds[2][8];
        #pragma unroll
        for (int st = 0; st < 2; ++st)
            #pragma unroll
            for (int i = 0; i < 8; ++i) {
                f16x2 p2; p2.x = (_Float16)sf[st][2 * i]; p2.y = (_Float16)sf[st][2 * i + 1];
                wds[st][i] = __builtin_bit_cast(int, p2);
            }
        #pragma unroll
        for (int st = 0; st < 2; ++st) {
            plswap(wds[st][0], wds[st][2]);
            plswap(wds[st][1], wds[st][3]);
            plswap(wds[st][4], wds[st][6]);
            plswap(wds[st][5], wds[st][7]);
        }

        // ---- O^T += V^T · P^T ----
        __builtin_amdgcn_s_setprio(1);
        #pragma unroll
        for (int st = 0; st < 2; ++st)
            #pragma unroll
            for (int ks2 = 0; ks2 < 2; ++ks2) {
                union { int i[4]; f16x8 v; } pu;
                #pragma unroll
                for (int k = 0; k < 4; ++k) pu.i[k] = wds[st][ks2 * 4 + k];
                #pragma unroll
                for (int dt = 0; dt < 2; ++dt) {
                    int dr = dt * 32 + ln;
                    f16x8 vf = *(const f16x8*)
                        &lds.st.V[cur][dr * 64 + (((st * 4 + ks2 * 2 + hi) ^ (dr & 7)) * 8)];
                    oacc[dt] = __builtin_amdgcn_mfma_f32_32x32x16_f16(vf, pu.v, oacc[dt], 0, 0, 0);
                }
            }
        __builtin_amdgcn_s_setprio(0);
        __syncthreads();
    }
#undef STAGE

    // ---- epilogue: normalize, re-tile via LDS, coalesced 16B stores ----
    float inv = 1.f / lr;
    #pragma unroll
    for (int dt = 0; dt < 2; ++dt)
        #pragma unroll
        for (int rq = 0; rq < 4; ++rq) {
            f16x4 v;
            #pragma unroll
            for (int k = 0; k < 4; ++k)
                v[k] = (_Float16)(oacc[dt][rq * 4 + k] * inv);
            int d0 = dt * 32 + rq * 8 + hi * 4;
            *(f16x4*)&lds.ot[w][ln * 72 + d0] = v;
        }
    __syncthreads();
    #pragma unroll
    for (int it = 0; it < 4; ++it) {
        int i = it * 256 + tid;
        int q = i >> 3, s = i & 7;
        f16x8 v = *(const f16x8*)&lds.ot[q >> 5][(q & 31) * 72 + s * 8];
        *(f16x8*)(Ah + ((size_t)(b * NQ) + q0 + q) * IN_DIM + h * 64 + s * 8) = v;
    }
}

// ---------------------------------------------------------------------------
extern "C" void kernel_launch(void* const* d_in, const int* in_sizes, int n_in,
                              void* d_out, int out_size, void* d_ws, size_t ws_size,
                              hipStream_t stream)
{
    const float* x   = (const float*)d_in[0];
    const float* ctx = (const float*)d_in[1];
    const float* Wq  = (const float*)d_in[2];
    const float* bq  = (const float*)d_in[3];
    const float* Wk  = (const float*)d_in[4];
    const float* bk  = (const float*)d_in[5];
    const float* Wv  = (const float*)d_in[6];
    const float* bv  = (const float*)d_in[7];
    const float* Wo  = (const float*)d_in[8];
    const float* bo  = (const float*)d_in[9];
    float* out = (float*)d_out;

    // fp16 workspace layout (halfword offsets)
    _Float16* H = (_Float16*)d_ws;
    _Float16* xh   = H +        0;  // x      8388608
    _Float16* ctxh = H +  8388608;  // ctx    3145728
    _Float16* wqh  = H + 11534336;  // Wq*C2LOG 1048576
    _Float16* wkh  = H + 12582912;  // Wk      786432
    _Float16* wvh  = H + 13369344;  // Wv      786432
    _Float16* woh  = H + 14155776;  // Wo     1048576
    _Float16* Qh   = H + 15204352;  // Q      8388608
    _Float16* Kh   = H + 23592960;  // K      4194304
    _Float16* Vth  = H + 31981568;  // V^T    4194304
    _Float16* Ah   = H + 36175872;  // attn-out 8388608

    // 1) fp32 -> fp16 (Wq segment pre-scaled by SCALE*log2e)
    cvt6<<<2048, 256, 0, stream>>>(x, ctx, Wq, Wk, Wv, Wo, xh);

    // 2) merged Q/K/V projections (V writes V^T directly)
    proj_qkv<<<1024, 256, 0, stream>>>(xh, ctxh, wqh, bq, wkh, bk, wvh, bv,
                                       Qh, Kh, Vth);

    // 3) attention (1024 blocks: 8 qt x 16 h x 8 b)
    attn_mfma<<<1024, 256, 0, stream>>>(Qh, Kh, Vth, Ah);

    // 4) output projection (fp32 out)
    gemm_out<<<512, 256, 0, stream>>>(Ah, woh, bo, out);
}